// Round 1
// 3191.186 us; speedup vs baseline: 1.2810x; 1.2810x over previous
//
#include <hip/hip_runtime.h>
#include <cstdint>

typedef _Float16 f16;
typedef _Float16 f16x8 __attribute__((ext_vector_type(8)));
typedef float    f32x4 __attribute__((ext_vector_type(4)));

#define DINL __device__ __forceinline__

static constexpr int HID = 1024;
static constexpr int NG  = 4096;   // 4*HID gate count
static constexpr int BB  = 256;    // batch
static constexpr int TT  = 100;    // seq len
static constexpr int KX  = 256;    // padded input-feature K (227 -> 256)
static constexpr size_t MSZ = (size_t)NG * HID;   // halves per packed [4096][1024] mat

// ---- workspace layout (bytes). total ~119 MiB ----
static constexpr size_t OFF_PACKW5 = 0;
static constexpr size_t OFF_W1D    = OFF_PACKW5 + 5*MSZ*2;
static constexpr size_t OFF_WIH1   = OFF_W1D   + MSZ*2;
static constexpr size_t OFF_WD     = OFF_WIH1  + (size_t)NG*KX*2;
static constexpr size_t OFF_XPAD   = OFF_WD    + (size_t)256*HID*2;
static constexpr size_t OFF_BIAS   = OFF_XPAD  + (size_t)TT*BB*KX*2;
static constexpr size_t OFF_C      = OFF_BIAS  + (size_t)4*NG*4;
static constexpr size_t OFF_HBUF   = OFF_C     + (size_t)3*BB*HID*4;
static constexpr size_t OFF_H2Z    = OFF_HBUF  + (size_t)4*BB*HID*2;
static constexpr size_t OFF_H2ALL  = OFF_H2Z   + (size_t)BB*HID*2;
// WdT scratch ([1024][256] f16) lives at OFF_H2ALL until k_w1d consumes it.

DINL void async16(void* lds, const void* g){
  auto lp = reinterpret_cast<__attribute__((address_space(3))) unsigned int*>(
      reinterpret_cast<uintptr_t>(lds));
  auto gp = reinterpret_cast<const __attribute__((address_space(1))) unsigned int*>(
      reinterpret_cast<uintptr_t>(g));
  __builtin_amdgcn_global_load_lds(gp, lp, 16, 0, 0);
}

// LDS read via inline asm: invisible to the compiler's LDS-DMA waitcnt pass
// (prevents it from inserting s_waitcnt vmcnt(0) before aliasing ds_reads).
DINL f16x8 ldsr128(unsigned a){
  f16x8 r;
  asm volatile("ds_read_b128 %0, %1" : "=v"(r) : "v"(a));
  return r;
}

DINL float sigf(float x){
  x = fminf(fmaxf(x, -30.f), 30.f);
  return __fdividef(1.f, 1.f + __expf(-x));
}
DINL float tanh_fast(float x){
  x = fminf(fmaxf(x, -15.f), 15.f);
  float t = __expf(2.f*x);
  return __fdividef(t - 1.f, t + 1.f);
}

// ---- single-buffered 128x128 tile core (k_w1d / k_final only) ----
DINL void gemm_tile(f32x4 acc[4][4],
                    const f16* __restrict__ A, int m0, int sA,
                    const f16* __restrict__ Bp, int n0, int K,
                    char* ldsA, char* ldsB, int w, int lane)
{
  const int m_w = (w>>1)*64, n_w = (w&1)*64, c15 = lane&15;
  for (int k0 = 0; k0 < K; k0 += 64){
    __syncthreads();
    #pragma unroll
    for (int q = 0; q < 4; q++){
      int r0  = w*32 + q*8;
      int row = r0 + (lane>>3);
      int kg  = (lane&7) ^ (row&7);
      async16(ldsA + r0*128, A  + (size_t)(m0+row)*sA + k0 + kg*8);
      async16(ldsB + r0*128, Bp + (size_t)(n0+row)*K  + k0 + kg*8);
    }
    __syncthreads();
    #pragma unroll
    for (int kw = 0; kw < 2; kw++){
      f16x8 af[4], bf[4];
      #pragma unroll
      for (int ti = 0; ti < 4; ti++){
        int row  = m_w + ti*16 + c15;
        int phys = (kw*4 + (lane>>4)) ^ (row&7);
        af[ti] = *(const f16x8*)(ldsA + row*128 + phys*16);
      }
      #pragma unroll
      for (int tj = 0; tj < 4; tj++){
        int row  = n_w + tj*16 + c15;
        int phys = (kw*4 + (lane>>4)) ^ (row&7);
        bf[tj] = *(const f16x8*)(ldsB + row*128 + phys*16);
      }
      #pragma unroll
      for (int ti = 0; ti < 4; ti++)
        #pragma unroll
        for (int tj = 0; tj < 4; tj++)
          acc[ti][tj] = __builtin_amdgcn_mfma_f32_16x16x32_f16(af[ti], bf[tj], acc[ti][tj], 0, 0, 0);
    }
  }
}

// ================= prep kernels =================

__global__ void k_pack5(const float* W0, const float* W1, const float* W2,
                        const float* W3, const float* W4, char* ws)
{
  f16* dst = (f16*)(ws + OFF_PACKW5);
  const int mat = blockIdx.y;
  const float* src = mat==0?W0 : mat==1?W1 : mat==2?W2 : mat==3?W3 : W4;
  int tid = blockIdx.x*256 + threadIdx.x;
  int n = tid >> 7, kc = tid & 127;
  int r = ((n&3) << 10) + (n >> 2);
  const float* s = src + (size_t)r*HID + kc*8;
  f16x8 o;
  #pragma unroll
  for (int i = 0; i < 8; i++) o[i] = (f16)s[i];
  *(f16x8*)(dst + (size_t)mat*MSZ + (size_t)n*HID + kc*8) = o;
}

__global__ void k_packwih1(const float* __restrict__ Wih1, char* ws){
  f16* dst = (f16*)(ws + OFF_WIH1);
  int n = blockIdx.x, k = threadIdx.x;
  int r = ((n&3) << 10) + (n >> 2);
  dst[(size_t)n*KX + k] = (k < 227) ? (f16)Wih1[(size_t)r*227 + k] : (f16)0.f;
}

__global__ void k_packwd(const float* __restrict__ Wd, char* ws){
  f16* dst = (f16*)(ws + OFF_WD);
  int o = blockIdx.x;
  #pragma unroll
  for (int j = 0; j < 4; j++){
    int k = threadIdx.x + j*256;
    dst[(size_t)o*HID + k] = (o < 227) ? (f16)Wd[(size_t)o*HID + k] : (f16)0.f;
  }
}

__global__ void k_packwdt(const float* __restrict__ Wd, char* ws){
  f16* dst = (f16*)(ws + OFF_H2ALL);
  int h = blockIdx.x, o = threadIdx.x;
  dst[(size_t)h*KX + o] = (o < 227) ? (f16)Wd[(size_t)o*HID + h] : (f16)0.f;
}

__global__ void k_xpad(const float* __restrict__ seq, char* ws){
  f16* dst = (f16*)(ws + OFF_XPAD);
  int idx = blockIdx.x*256 + threadIdx.x;
  int t = idx >> 16, rem = idx & 65535, b = rem >> 8, k = rem & 255;
  dst[idx] = (k < 227) ? (f16)seq[(size_t)b*22700 + (size_t)t*227 + k] : (f16)0.f;
}

__global__ void k_bias(const float* bih1, const float* bhh1, const float* bih2, const float* bhh2,
                       const float* bih3, const float* bhh3, const float* Wih1, const float* bd,
                       char* ws)
{
  int n = blockIdx.x*256 + threadIdx.x;
  if (n >= NG) return;
  int r = ((n&3) << 10) + (n >> 2);
  float* b = (float*)(ws + OFF_BIAS);
  float bf = bih1[r] + bhh1[r];
  float s = 0.f;
  for (int o = 0; o < 227; o++) s += Wih1[(size_t)r*227 + o] * bd[o];
  b[n]        = bf;
  b[NG + n]   = bf + s;
  b[2*NG + n] = bih2[r] + bhh2[r];
  b[3*NG + n] = bih3[r] + bhh3[r];
}

__global__ __launch_bounds__(256, 2) void k_w1d(char* ws)
{
  __shared__ __align__(16) char ldsA[16384];
  __shared__ __align__(16) char ldsB[16384];
  const int w = threadIdx.x >> 6, lane = threadIdx.x & 63;
  const int n0 = blockIdx.x*128, m0 = blockIdx.y*128;
  const f16* A  = (const f16*)(ws + OFF_WIH1);
  const f16* Bp = (const f16*)(ws + OFF_H2ALL);
  f16* W1D = (f16*)(ws + OFF_W1D);

  f32x4 acc[4][4];
  f32x4 zero = {0.f, 0.f, 0.f, 0.f};
  #pragma unroll
  for (int i = 0; i < 4; i++)
    #pragma unroll
    for (int j = 0; j < 4; j++) acc[i][j] = zero;

  gemm_tile(acc, A, m0, KX, Bp, n0, KX, ldsA, ldsB, w, lane);

  const int m_w = (w>>1)*64, n_w = (w&1)*64, quad = lane>>4, c15 = lane&15;
  #pragma unroll
  for (int tj = 0; tj < 4; tj++){
    int col = n0 + n_w + tj*16 + c15;
    #pragma unroll
    for (int ti = 0; ti < 4; ti++){
      f32x4 v = acc[ti][tj];
      #pragma unroll
      for (int r = 0; r < 4; r++){
        int m = m0 + m_w + ti*16 + quad*4 + r;
        W1D[(size_t)m*HID + col] = (f16)v[r];
      }
    }
  }
}

// ================= recurrent step kernel =================
// 512 threads = 8 waves (2 waves/SIMD), grid (64 ntiles, 3 layers).
// Tm=256 x Tn=64, BK=64. Wave tile 32x64 (per-wave-private A rows).
// LDS (160KB exact):
//   [0, 64KB)   : B ring, 8 chunk-slabs x 8KB (shared; barrier every 4 chunks)
//   [64K,160K)  : A, per-wave 3 private buffers x 4KB (NO barrier; issue 2-ahead)
// Per-iter vm-ops (in order): [1 B-instr][4 A-instrs]. Hand-derived waits:
//   steady vmcnt(5); barrier iters (c%4==0) and tail vmcnt(4); last vmcnt(0).
// B-group g+1 (chunks 4g+4..4g+7 -> slabs disjoint from readable 4g..4g+3) is
// issued spread over iters 4g..4g+3, strictly after the barrier at 4g, so the
// ring is race-free for any wave skew within a group window.
__global__ __launch_bounds__(512, 2) void k_step(char* __restrict__ ws, int t, int use_gt)
{
  __shared__ __align__(16) char lds[163840];
  const int w = threadIdx.x >> 6, lane = threadIdx.x & 63;
  const int col0 = blockIdx.x*64, layer = blockIdx.y;

  const f16* packW = (const f16*)(ws + OFF_PACKW5);
  const f16* W1D   = (const f16*)(ws + OFF_W1D);
  const f16* WIH1  = (const f16*)(ws + OFF_WIH1);
  const f16* XP    = (const f16*)(ws + OFF_XPAD) + (size_t)t*BB*KX;
  const float* biasb = (const float*)(ws + OFF_BIAS);
  float* Cst = (float*)(ws + OFF_C);
  f16* HB  = (f16*)(ws + OFF_HBUF);
  f16* H2Z = (f16*)(ws + OFF_H2Z);
  f16* H2A = (f16*)(ws + OFF_H2ALL);

  const int pr = t & 1, pw = pr ^ 1;
  const f16* h0p = HB + (size_t)(pr*2 + 0)*BB*HID;
  const f16* h1p = HB + (size_t)(pr*2 + 1)*BB*HID;
  const f16* h2p = (t == 0) ? H2Z : (H2A + (size_t)(t-1)*BB*HID);

  const f16 *A0, *A1, *B0, *B1; int K1, sA1;
  const float* biasp; f16* hout; float* cptr;
  if (layer == 0){
    A0 = h0p; B0 = packW;
    if (use_gt){ A1 = XP;  B1 = WIH1; K1 = KX;  sA1 = KX;  biasp = biasb; }
    else       { A1 = h2p; B1 = W1D;  K1 = HID; sA1 = HID; biasp = biasb + NG; }
    hout = HB + (size_t)(pw*2 + 0)*BB*HID; cptr = Cst;
  } else if (layer == 1){
    A0 = h0p; B0 = packW + MSZ;  A1 = h1p; B1 = packW + 2*MSZ; K1 = HID; sA1 = HID;
    biasp = biasb + 2*NG; hout = HB + (size_t)(pw*2 + 1)*BB*HID; cptr = Cst + (size_t)BB*HID;
  } else {
    A0 = h1p; B0 = packW + 3*MSZ; A1 = h2p; B1 = packW + 4*MSZ; K1 = HID; sA1 = HID;
    biasp = biasb + 3*NG; hout = H2A + (size_t)t*BB*HID; cptr = Cst + (size_t)2*BB*HID;
  }
  const int ncmax = 16 + (K1 >> 6);   // 32 (or 20 for layer0/ug)

  const int rsub = lane >> 3;
  const int kxe  = ((lane & 7) ^ rsub) * 8;   // XOR-swizzled k-chunk (elements)

  // A: per-wave-private rows [w*32, w*32+32), 3 buffers of 4KB at 64KB + w*12KB
  auto issueA = [&](int cc, int buf){
    const f16* src; int strd;
    if (cc < 16){ src = A0 + (size_t)cc*64;      strd = HID; }
    else        { src = A1 + (size_t)(cc-16)*64; strd = sA1; }
    char* dst = lds + 65536 + w*12288 + buf*4096;
    #pragma unroll
    for (int q = 0; q < 4; q++)
      async16(dst + q*1024, src + (size_t)(w*32 + q*8 + rsub)*strd + kxe);
  };
  // B: shared ring of 8 chunk-slabs (8KB each). One 1KB instr per wave per iter;
  // wave w covers chunk base+(w>>1), row-block j=(w&1)*4+k.
  auto issueB = [&](int chunk, int j){
    const f16* src; int strd;
    if (chunk < 16){ src = B0 + (size_t)chunk*64;      strd = HID; }
    else           { src = B1 + (size_t)(chunk-16)*64; strd = K1;  }
    async16(lds + (chunk & 7)*8192 + j*1024,
            src + (size_t)(col0 + j*8 + rsub)*strd + kxe);
  };

  f32x4 acc[2][4];
  f32x4 zero = {0.f, 0.f, 0.f, 0.f};
  #pragma unroll
  for (int i = 0; i < 2; i++)
    #pragma unroll
    for (int j = 0; j < 4; j++) acc[i][j] = zero;

  const int m_w = w*32, c15 = lane&15, quad = lane>>4;

  // (row & 7) == (c15 & 7) for every fragment row -> swizzle phase per-lane const
  const unsigned ldsBase = (unsigned)(uintptr_t)lds;
  const unsigned p0 = (unsigned)(( quad      ^ (c15&7)) * 16);   // kw=0 phase
  const unsigned p1 = (unsigned)(((4 + quad) ^ (c15&7)) * 16);   // kw=1 phase
  unsigned rA[2], rB[4];
  #pragma unroll
  for (int ti = 0; ti < 2; ti++) rA[ti] = (unsigned)((ti*16 + c15) * 128);
  #pragma unroll
  for (int tj = 0; tj < 4; tj++) rB[tj] = (unsigned)((tj*16 + c15) * 128);

  // prologue: B group 0 (chunks 0..3) fully, then A chunks 0,1.
  {
    const int cb = w >> 1, jb = (w & 1) * 4;
    #pragma unroll
    for (int k = 0; k < 4; k++) issueB(cb, jb + k);
  }
  issueA(0, 0); issueA(1, 1);

  int bR = 0, bW = 2;   // A buffer indices: read = c%3, write = (c+2)%3
  for (int c = 0; c < ncmax; c++){
    if (c == ncmax-1)                    asm volatile("s_waitcnt vmcnt(0)" ::: "memory");
    else if ((c&3)==0 || c >= ncmax-4)   asm volatile("s_waitcnt vmcnt(4)" ::: "memory");
    else                                 asm volatile("s_waitcnt vmcnt(5)" ::: "memory");
    if ((c & 3) == 0) __builtin_amdgcn_s_barrier();   // publish B group c>>2
    if (c <= ncmax-5) issueB(4*((c>>2)+1) + (w>>1), (w&1)*4 + (c&3));
    if (c <= ncmax-3) issueA(c+2, bW);

    const unsigned ab = ldsBase + 65536u + (unsigned)(w*12288) + (unsigned)(bR*4096);
    const unsigned bb = ldsBase + (unsigned)((c & 7) * 8192);

    f16x8 a0[2], b0[4], a1[2], b1[4];
    #pragma unroll
    for (int ti = 0; ti < 2; ti++) a0[ti] = ldsr128(ab + rA[ti] + p0);
    #pragma unroll
    for (int tj = 0; tj < 4; tj++) b0[tj] = ldsr128(bb + rB[tj] + p0);
    #pragma unroll
    for (int ti = 0; ti < 2; ti++) a1[ti] = ldsr128(ab + rA[ti] + p1);
    #pragma unroll
    for (int tj = 0; tj < 4; tj++) b1[tj] = ldsr128(bb + rB[tj] + p1);

    asm volatile("s_waitcnt lgkmcnt(6)"
      : "+v"(a0[0]), "+v"(a0[1]),
        "+v"(b0[0]), "+v"(b0[1]), "+v"(b0[2]), "+v"(b0[3]));
    #pragma unroll
    for (int ti = 0; ti < 2; ti++)
      #pragma unroll
      for (int tj = 0; tj < 4; tj++)
        acc[ti][tj] = __builtin_amdgcn_mfma_f32_16x16x32_f16(a0[ti], b0[tj], acc[ti][tj], 0, 0, 0);

    asm volatile("s_waitcnt lgkmcnt(0)"
      : "+v"(a1[0]), "+v"(a1[1]),
        "+v"(b1[0]), "+v"(b1[1]), "+v"(b1[2]), "+v"(b1[3]));
    #pragma unroll
    for (int ti = 0; ti < 2; ti++)
      #pragma unroll
      for (int tj = 0; tj < 4; tj++)
        acc[ti][tj] = __builtin_amdgcn_mfma_f32_16x16x32_f16(a1[ti], b1[tj], acc[ti][tj], 0, 0, 0);

    bR = (bR == 2) ? 0 : bR + 1;
    bW = (bW == 2) ? 0 : bW + 1;
  }

  // ---- fused LSTM cell epilogue (per-lane single activation, shuffle after) ----
  const int gl = lane&3, sbase = lane&60;
  #pragma unroll
  for (int tj = 0; tj < 4; tj++){
    const int ncol = col0 + tj*16 + c15;
    const int unit = ncol >> 2;
    const float bn = biasp[ncol];
    float cp[8];
    #pragma unroll
    for (int ti = 0; ti < 2; ti++)
      #pragma unroll
      for (int r = 0; r < 4; r++)
        cp[ti*4 + r] = cptr[(size_t)(m_w + ti*16 + quad*4 + r)*HID + unit];
    #pragma unroll
    for (int ti = 0; ti < 2; ti++){
      f32x4 v = acc[ti][tj];
      #pragma unroll
      for (int r = 0; r < 4; r++){
        float x   = v[r] + bn;
        float act = (gl == 2) ? tanh_fast(x) : sigf(x);   // lane's own gate only
        float iv = __shfl(act, sbase);
        float fv = __shfl(act, sbase + 1);
        float gv = __shfl(act, sbase + 2);
        float ov = __shfl(act, sbase + 3);
        float cn = fmaf(fv, cp[ti*4 + r], iv*gv);
        float hn = ov * tanh_fast(cn);
        int m = m_w + ti*16 + quad*4 + r;
        if (gl == 0)      cptr[(size_t)m*HID + unit] = cn;
        else if (gl == 1) hout[(size_t)m*HID + unit] = (f16)hn;
      }
    }
  }
}

// ================= final output GEMM =================
__global__ __launch_bounds__(256, 2) void k_final(const char* __restrict__ ws,
                                                  const float* __restrict__ bd,
                                                  float* __restrict__ dout)
{
  __shared__ __align__(16) char ldsA[16384];
  __shared__ __align__(16) char ldsB[16384];
  const int w = threadIdx.x >> 6, lane = threadIdx.x & 63;
  const int n0 = blockIdx.x*128, m0 = blockIdx.y*128;
  const f16* A  = (const f16*)(ws + OFF_H2ALL);
  const f16* Bp = (const f16*)(ws + OFF_WD);

  f32x4 acc[4][4];
  f32x4 zero = {0.f, 0.f, 0.f, 0.f};
  #pragma unroll
  for (int i = 0; i < 4; i++)
    #pragma unroll
    for (int j = 0; j < 4; j++) acc[i][j] = zero;

  gemm_tile(acc, A, m0, HID, Bp, n0, HID, ldsA, ldsB, w, lane);

  const int m_w = (w>>1)*64, n_w = (w&1)*64, quad = lane>>4, c15 = lane&15;
  #pragma unroll
  for (int tj = 0; tj < 4; tj++){
    int o = n0 + n_w + tj*16 + c15;
    bool valid = (o < 227);
    float bn = valid ? bd[o] : 0.f;
    #pragma unroll
    for (int ti = 0; ti < 4; ti++){
      f32x4 v = acc[ti][tj];
      #pragma unroll
      for (int r = 0; r < 4; r++){
        int m = m0 + m_w + ti*16 + quad*4 + r;
        if (valid){
          int tt = m >> 8, b = m & 255;
          dout[(size_t)b*22700 + (size_t)tt*227 + o] = v[r] + bn;
        }
      }
    }
  }
}

// ================= host =================
extern "C" void kernel_launch(void* const* d_in, const int* in_sizes, int n_in,
                              void* d_out, int out_size, void* d_ws, size_t ws_size,
                              hipStream_t stream)
{
  (void)in_sizes; (void)n_in; (void)out_size; (void)ws_size;
  const float* seq  = (const float*)d_in[0];
  const float* Wih1 = (const float*)d_in[1];
  const float* Whh1 = (const float*)d_in[2];
  const float* bih1 = (const float*)d_in[3];
  const float* bhh1 = (const float*)d_in[4];
  const float* Wih2 = (const float*)d_in[5];
  const float* Whh2 = (const float*)d_in[6];
  const float* bih2 = (const float*)d_in[7];
  const float* bhh2 = (const float*)d_in[8];
  const float* Wih3 = (const float*)d_in[9];
  const float* Whh3 = (const float*)d_in[10];
  const float* bih3 = (const float*)d_in[11];
  const float* bhh3 = (const float*)d_in[12];
  const float* Wd   = (const float*)d_in[13];
  const float* bd   = (const float*)d_in[14];
  char* ws = (char*)d_ws;

  hipMemsetAsync(ws + OFF_C,    0, (size_t)3*BB*HID*4, stream);
  hipMemsetAsync(ws + OFF_HBUF, 0, (size_t)2*BB*HID*2, stream);
  hipMemsetAsync(ws + OFF_H2Z,  0, (size_t)BB*HID*2,   stream);

  k_pack5   <<<dim3(2048, 5), dim3(256), 0, stream>>>(Whh1, Wih2, Whh2, Wih3, Whh3, ws);
  k_packwih1<<<dim3(4096),    dim3(256), 0, stream>>>(Wih1, ws);
  k_packwd  <<<dim3(256),     dim3(256), 0, stream>>>(Wd, ws);
  k_packwdt <<<dim3(1024),    dim3(256), 0, stream>>>(Wd, ws);
  k_xpad    <<<dim3(25600),   dim3(256), 0, stream>>>(seq, ws);
  k_bias    <<<dim3(16),      dim3(256), 0, stream>>>(bih1, bhh1, bih2, bhh2, bih3, bhh3, Wih1, bd, ws);
  k_w1d     <<<dim3(8, 32),   dim3(256), 0, stream>>>(ws);

  for (int t = 0; t < TT; t++){
    int ug = ((t % 10) < 5) ? 1 : 0;
    k_step<<<dim3(64, 3), dim3(512), 0, stream>>>(ws, t, ug);
  }

  k_final<<<dim3(2, 200), dim3(256), 0, stream>>>((const char*)ws, bd, (float*)d_out);
}